// Round 2
// baseline (326.920 us; speedup 1.0000x reference)
//
#include <hip/hip_runtime.h>
#include <hip/hip_bf16.h>

// BoltzmannRouter: weights = renorm(top44(softmax(x @ gate_w^T / e)))
// x: (4,4096,2048) f32 ; gate_w: (64,2048) f32 ; out: (4,4096,64) f32
//
// f64-accumulation fused kernel: selection (top-44) must match an f64
// numpy reference; f32 chain error (~2e-6) flipped a borderline token in R1.
// Scores accumulated with v_fma_f64 (error ~1e-13), ranking in f64,
// softmax/renorm in f32 (output tolerance 3.77e-3).
//
// grid = 256 blocks (1/CU), 256 threads (4 waves), BM=64 tokens/block.
// LDS tiles staged via global_load_lds w=16 with XOR swizzle slot^=row>>2
// (pre-swizzled global source, linear LDS dest) -> conflict-free reads.

#define NTOK   16384
#define DIM    2048
#define NEXP   64
#define NACT   44
#define BM     64
#define BK     64
#define NSTEPS (DIM / BK)   // 32

__device__ __forceinline__ void gload16(const float* g, float* l) {
  __builtin_amdgcn_global_load_lds(
      (const __attribute__((address_space(1))) void*)g,
      (__attribute__((address_space(3))) void*)l, 16, 0, 0);
}

__global__ __launch_bounds__(256) void boltzmann_router_kernel(
    const float* __restrict__ x, const float* __restrict__ gw,
    float* __restrict__ out) {
  __shared__ float xs[2][BM * BK];    // 32 KB
  __shared__ float wsm[2][NEXP * BK]; // 32 KB

  const int t    = threadIdx.x;
  const int wv   = t >> 6;
  const int ln   = t & 63;
  const int tok0 = blockIdx.x * BM;

  // thread tile: 4 tokens x 4 experts
  const int tm = t & 15;      // token group 0..15
  const int te = t >> 4;      // expert group 0..15
  const int m0 = tm * 4, e0 = te * 4;

  double acc[4][4] = {};

  const int lrow = ln >> 4;   // 0..3
  const int lc16 = ln & 15;   // 16B-slot within row

  // ---- stage step 0 (pre-swizzled source: slot c holds data col c^chunk) ----
  #pragma unroll
  for (int i = 0; i < 4; ++i) {
    const int chunk = wv * 4 + i;            // 0..15, wave-uniform
    const int r = chunk * 4 + lrow;          // row within tile; r>>2 == chunk
    const int c = (lc16 ^ chunk) * 4;        // swizzled float col
    gload16(x  + (size_t)(tok0 + r) * DIM + c, &xs[0][chunk * 256]);
    gload16(gw + (size_t)r          * DIM + c, &wsm[0][chunk * 256]);
  }
  __syncthreads();

  for (int step = 0; step < NSTEPS; ++step) {
    const int cur = step & 1;
    if (step + 1 < NSTEPS) {
      const int k0 = (step + 1) * BK;
      const int nb = cur ^ 1;
      #pragma unroll
      for (int i = 0; i < 4; ++i) {
        const int chunk = wv * 4 + i;
        const int r = chunk * 4 + lrow;
        const int c = (lc16 ^ chunk) * 4;
        gload16(x  + (size_t)(tok0 + r) * DIM + k0 + c, &xs[nb][chunk * 256]);
        gload16(gw + (size_t)r          * DIM + k0 + c, &wsm[nb][chunk * 256]);
      }
    }
    const float4* xa = reinterpret_cast<const float4*>(&xs[cur][0]);
    const float4* wa = reinterpret_cast<const float4*>(&wsm[cur][0]);
    #pragma unroll 4
    for (int kk = 0; kk < 16; ++kk) {
      float4 a[4], b[4];
      #pragma unroll
      for (int m = 0; m < 4; ++m) a[m] = xa[(m0 + m) * 16 + (kk ^ tm)];
      #pragma unroll
      for (int e = 0; e < 4; ++e) b[e] = wa[(e0 + e) * 16 + (kk ^ te)];
      double bd[4][4];
      #pragma unroll
      for (int e = 0; e < 4; ++e) {
        bd[e][0] = (double)b[e].x; bd[e][1] = (double)b[e].y;
        bd[e][2] = (double)b[e].z; bd[e][3] = (double)b[e].w;
      }
      #pragma unroll
      for (int m = 0; m < 4; ++m) {
        const double ax = (double)a[m].x, ay = (double)a[m].y;
        const double az = (double)a[m].z, aw = (double)a[m].w;
        #pragma unroll
        for (int e = 0; e < 4; ++e) {
          acc[m][e] = fma(ax, bd[e][0], acc[m][e]);
          acc[m][e] = fma(ay, bd[e][1], acc[m][e]);
          acc[m][e] = fma(az, bd[e][2], acc[m][e]);
          acc[m][e] = fma(aw, bd[e][3], acc[m][e]);
        }
      }
    }
    __syncthreads();
  }

  // ---- epilogue: f64 scores -> rank (f64) + softmax/renorm (f32) ----
  double* sc = reinterpret_cast<double*>(&xs[0][0]); // 64x64 f64 = 32 KB
  const double INVT = 0.36787944117144233;           // 1/e
  #pragma unroll
  for (int m = 0; m < 4; ++m)
    #pragma unroll
    for (int e = 0; e < 4; ++e)
      sc[(m0 + m) * 64 + (e0 + e)] = acc[m][e] * INVT;
  __syncthreads();

  for (int it = 0; it < 16; ++it) {
    const int m = wv * 16 + it;
    const double s64 = sc[m * 64 + ln];

    // bitonic sort (ascending) of the 64 f64 scores across lanes
    double v = s64;
    #pragma unroll
    for (int k = 2; k <= 64; k <<= 1) {
      #pragma unroll
      for (int j = k >> 1; j > 0; j >>= 1) {
        const double o  = __shfl_xor(v, j, 64);
        const bool up  = ((ln & k) == 0);
        const bool low = ((ln & j) == 0);
        v = (low == up) ? fmin(v, o) : fmax(v, o);
      }
    }
    const double thr = __shfl(v, 64 - NACT, 64); // 21st smallest
    const bool sel = (s64 >= thr);

    // softmax in f32 (shared max/denominator over all 64)
    const float s = (float)s64;
    float mx = s;
    #pragma unroll
    for (int j = 32; j > 0; j >>= 1) mx = fmaxf(mx, __shfl_xor(mx, j, 64));
    const float ex = __expf(s - mx);
    float sum = ex;
    #pragma unroll
    for (int j = 32; j > 0; j >>= 1) sum += __shfl_xor(sum, j, 64);
    const float p = ex / sum;

    float ps = sel ? p : 0.0f;
    #pragma unroll
    for (int j = 32; j > 0; j >>= 1) ps += __shfl_xor(ps, j, 64);

    out[(size_t)(tok0 + m) * NEXP + ln] = sel ? (p / (ps + 1e-8f)) : 0.0f;
  }
}

extern "C" void kernel_launch(void* const* d_in, const int* in_sizes, int n_in,
                              void* d_out, int out_size, void* d_ws, size_t ws_size,
                              hipStream_t stream) {
  const float* x  = (const float*)d_in[0];
  const float* gw = (const float*)d_in[1];
  float* out = (float*)d_out;
  boltzmann_router_kernel<<<dim3(NTOK / BM), dim3(256), 0, stream>>>(x, gw, out);
}